// Round 12
// baseline (124.087 us; speedup 1.0000x reference)
//
#include <hip/hip_runtime.h>
#include <hip/hip_bf16.h>

#define TOT 66560
#define NQ 1024
#define DIM 512
#define K_SEL 3328
#define NBK 32  // buckets per row

typedef int i32x8 __attribute__((ext_vector_type(8)));
typedef float f32x4 __attribute__((ext_vector_type(4)));

__device__ __forceinline__ void gload_lds16(const void* g, void* l) {
  __builtin_amdgcn_global_load_lds(
      (const __attribute__((address_space(1))) unsigned int*)g,
      (__attribute__((address_space(3))) unsigned int*)l, 16, 0, 0);
}

// fp4 e2m1 encode, nearest: levels {0,0.5,1,1.5,2,3,4,6} = codes 0..7, sign<<3
__device__ __forceinline__ unsigned int fp4enc(float v) {
  float a = fabsf(v);
  unsigned int idx = (a > 0.25f) + (a > 0.75f) + (a > 1.25f) + (a > 1.75f) +
                     (a > 2.5f) + (a > 3.5f) + (a > 5.0f);
  return ((v < 0.f) ? 8u : 0u) | idx;
}

// ---------------- normalize rows -> fp4 matrix F4 (TOT x 512, 256 B/row) --
// values stored as 32*x (scale baked in); 8 elems -> one u32 per lane.
__global__ __launch_bounds__(256) void norm_kernel(
    const float* __restrict__ inputs, const float* __restrict__ bank,
    unsigned int* __restrict__ F4) {
  int row = blockIdx.x * 4 + (threadIdx.x >> 6);
  int lane = threadIdx.x & 63;
  const float* src = (row < NQ) ? (inputs + (size_t)row * DIM)
                                : (bank + (size_t)(row - NQ) * DIM);
  const float4 a = *(const float4*)(src + lane * 8);
  const float4 b = *(const float4*)(src + lane * 8 + 4);
  float ss = a.x * a.x + a.y * a.y + a.z * a.z + a.w * a.w +
             b.x * b.x + b.y * b.y + b.z * b.z + b.w * b.w;
#pragma unroll
  for (int off = 1; off < 64; off <<= 1) ss += __shfl_xor(ss, off);
  float sc = 32.0f / fmaxf(sqrtf(ss), 1e-12f);
  unsigned int w = fp4enc(a.x * sc) | (fp4enc(a.y * sc) << 4) |
                   (fp4enc(a.z * sc) << 8) | (fp4enc(a.w * sc) << 12) |
                   (fp4enc(b.x * sc) << 16) | (fp4enc(b.y * sc) << 20) |
                   (fp4enc(b.z * sc) << 24) | (fp4enc(b.w * sc) << 28);
  F4[(size_t)row * 64 + lane] = w;
}

// ------------- pack labels to 4-bit nibbles + zero ph accumulator ---------
__global__ __launch_bounds__(256) void pack_kernel(
    const int* __restrict__ gt, const int* __restrict__ bl,
    unsigned int* __restrict__ lab4, unsigned int* __restrict__ ph) {
  int i = blockIdx.x * 256 + threadIdx.x;
  if (i < TOT / 8) {
    unsigned int w = 0;
#pragma unroll
    for (int e = 0; e < 8; ++e) {
      int c = i * 8 + e;
      int l = (c < NQ) ? gt[c] : bl[c - NQ];
      w |= ((unsigned int)l & 0xFu) << (4 * e);
    }
    lab4[i] = w;
  }
  // zero ph: NQ*NBK = 32768 words; grid 64 blocks x 256 = 16384 threads
  for (int j = i; j < NQ * NBK; j += 64 * 256) ph[j] = 0;
}

// ---------------- fused GEMM + per-row bucket histogram -------------------
// 128x128 tile, 4 waves, wave 64x64, acc[4][4]. Entire K=512 staged once,
// one barrier, 4x16 mfma_scale fp4. Epilogue: per-row 32-bucket LDS hist
// (cnt|same<<16) of the tile, then global atomic merge into ph[1024][32].
// No S matrix is ever materialized.
__global__ __launch_bounds__(256, 2) void gemm_kernel(
    const unsigned char* __restrict__ F4, const int* __restrict__ gt,
    const unsigned int* __restrict__ lab4, unsigned int* __restrict__ ph) {
  __shared__ unsigned char smem[65536];  // A[128][256B] | B[128][256B]

  // XCD-aware swizzle: 4160 blocks, 8 XCDs, 520 per XCD, bm fastest.
  int wgid = blockIdx.x;
  int xcd = wgid & 7;
  int local = wgid >> 3;
  int gid = xcd * 520 + local;
  int bm = gid & 7;   // row tile 0..7 (fastest: 8 blocks share a B panel)
  int bn = gid >> 3;  // col tile 0..519

  int tid = threadIdx.x;
  int lane = tid & 63, wave = tid >> 6;
  int wr = wave >> 1, wc = wave & 1;

  f32x4 acc[4][4];
#pragma unroll
  for (int m = 0; m < 4; ++m)
#pragma unroll
    for (int n = 0; n < 4; ++n) acc[m][n] = (f32x4){0.f, 0.f, 0.f, 0.f};

  int rowA0 = bm * 128;
  int rowB0 = bn * 128;

  // stage full K: rows are 256 B (16 chunks of 16 B); LDS dest linear,
  // global chunk = phys_chunk ^ (row & 15).
#pragma unroll
  for (int q = 0; q < 8; ++q) {
    int o = q * 4096 + tid * 16;
    int r = o >> 8;
    int cg = ((o >> 4) & 15) ^ (r & 15);
    gload_lds16(F4 + (size_t)(rowA0 + r) * 256 + cg * 16, smem + o);
  }
#pragma unroll
  for (int q = 0; q < 8; ++q) {
    int o = q * 4096 + tid * 16;
    int r = o >> 8;
    int cg = ((o >> 4) & 15) ^ (r & 15);
    gload_lds16(F4 + (size_t)(rowB0 + r) * 256 + cg * 16, smem + 32768 + o);
  }
  asm volatile("s_waitcnt vmcnt(0)" ::: "memory");
  __syncthreads();

  int g = lane >> 4;  // k-group 0..3 (32 k-elems = 16 B each)
  const unsigned char* At = smem;
  const unsigned char* Bt = smem + 32768;

#pragma unroll
  for (int t = 0; t < 4; ++t) {
    i32x8 af[4], bf[4];
#pragma unroll
    for (int m = 0; m < 4; ++m) {
      int r = wr * 64 + m * 16 + (lane & 15);
      int c = (4 * t + g) ^ (r & 15);
      uint4 v = *(const uint4*)(At + r * 256 + c * 16);
      af[m] = (i32x8){(int)v.x, (int)v.y, (int)v.z, (int)v.w, 0, 0, 0, 0};
    }
#pragma unroll
    for (int n = 0; n < 4; ++n) {
      int r = wc * 64 + n * 16 + (lane & 15);
      int c = (4 * t + g) ^ (r & 15);
      uint4 v = *(const uint4*)(Bt + r * 256 + c * 16);
      bf[n] = (i32x8){(int)v.x, (int)v.y, (int)v.z, (int)v.w, 0, 0, 0, 0};
    }
#pragma unroll
    for (int m = 0; m < 4; ++m)
#pragma unroll
      for (int n = 0; n < 4; ++n)
        acc[m][n] = __builtin_amdgcn_mfma_scale_f32_16x16x128_f8f6f4(
            af[m], bf[n], acc[m][n], 4 /*cbsz: fp4*/, 4 /*blgp: fp4*/,
            0, 0x7F7F7F7F /*scale A = 1.0*/, 0, 0x7F7F7F7F /*scale B = 1.0*/);
  }

  // ---- fused epilogue: per-row 32-bucket joint histogram of this tile ----
  // acc = 1024*sim. bucket = clamp(floor(sim/0.011) + 16, 0, 31); self skipped.
  // C layout: col=lane&15, row=(lane>>4)*4+e (shape-determined).
  __syncthreads();  // staging reads done; alias smem
  unsigned int* bh = (unsigned int*)smem;                 // [128][32] = 16 KB
  unsigned char* rl = (unsigned char*)(smem + 16384);     // 128 row labels
  for (int i = tid; i < 128 * NBK; i += 256) bh[i] = 0;
  if (tid < 128) rl[tid] = (unsigned char)(gt[bm * 128 + tid] & 0xF);
  __syncthreads();

  unsigned int clab[4];
#pragma unroll
  for (int n = 0; n < 4; ++n) {
    int gc = bn * 128 + wc * 64 + n * 16 + (lane & 15);
    clab[n] = (lab4[gc >> 3] >> ((gc & 7) * 4)) & 0xFu;
  }
#pragma unroll
  for (int m = 0; m < 4; ++m)
#pragma unroll
    for (int n = 0; n < 4; ++n)
#pragma unroll
      for (int e = 0; e < 4; ++e) {
        int rtile = wr * 64 + m * 16 + (lane >> 4) * 4 + e;  // 0..127
        int gr = bm * 128 + rtile;
        int gc = bn * 128 + wc * 64 + n * 16 + (lane & 15);
        if (gr != gc) {
          int b = (int)fmaf(acc[m][n][e], 0.088778409f, 16.0f);
          b = min(max(b, 0), NBK - 1);
          unsigned int inc = (clab[n] == (unsigned int)rl[rtile]) ? 0x10001u : 1u;
          atomicAdd(&bh[rtile * NBK + b], inc);
        }
      }
  __syncthreads();
  // merge non-zero buckets into global ph (device-scope atomics)
  for (int i = tid; i < 128 * NBK; i += 256) {
    unsigned int v = bh[i];
    if (v)
      atomicAdd(&ph[(size_t)(bm * 128 + (i >> 5)) * NBK + (i & 31)], v);
  }
}

// ---------------- per-row threshold scan (1 thread per row) ---------------
__global__ __launch_bounds__(256) void thresh_kernel(
    const unsigned int* __restrict__ ph, float* __restrict__ rowres) {
  int row = blockIdx.x * 256 + threadIdx.x;
  if (row >= NQ) return;
  const unsigned int* hr = ph + (size_t)row * NBK;
  unsigned int cum = 0, same = 0;
  float res = 0.f;
  for (int b = NBK - 1; b >= 0; --b) {
    unsigned int vv = hr[b];
    unsigned int cb = vv & 0xFFFFu, sb = vv >> 16;
    if (cum + cb >= (unsigned)K_SEL) {
      unsigned int need = (unsigned)K_SEL - cum;
      res = (float)same + (float)sb * ((float)need / (float)cb);
      break;
    }
    cum += cb;
    same += sb;
  }
  rowres[row] = res;
}

// ---------------- final reduction ----------------------------------------
__global__ __launch_bounds__(256) void final_kernel(const float* __restrict__ rowres,
                                                    float* __restrict__ out) {
  int tid = threadIdx.x;
  float s = 0.f;
  for (int i = tid; i < NQ; i += 256) s += rowres[i];
  for (int off = 32; off; off >>= 1) s += __shfl_down(s, off);
  __shared__ float part[4];
  if ((tid & 63) == 0) part[tid >> 6] = s;
  __syncthreads();
  if (tid == 0) {
    float total = part[0] + part[1] + part[2] + part[3];
    out[0] = 1.0f - total / ((float)NQ * (float)K_SEL);
  }
}

extern "C" void kernel_launch(void* const* d_in, const int* in_sizes, int n_in,
                              void* d_out, int out_size, void* d_ws, size_t ws_size,
                              hipStream_t stream) {
  const float* inputs = (const float*)d_in[0];
  const int* gt = (const int*)d_in[1];
  const float* bank = (const float*)d_in[2];
  const int* bl = (const int*)d_in[3];
  float* out = (float*)d_out;

  char* ws = (char*)d_ws;
  const size_t F_OFF = 0;
  const size_t F_BYTES = (size_t)TOT * 256;  // 17,039,360 (fp4)
  const size_t PH_OFF = F_OFF + F_BYTES;
  const size_t PH_BYTES = (size_t)NQ * NBK * 4;  // 131,072
  const size_t RR_OFF = PH_OFF + PH_BYTES;
  const size_t RR_BYTES = 4096;
  const size_t L4_OFF = RR_OFF + RR_BYTES;

  unsigned int* F4 = (unsigned int*)(ws + F_OFF);
  unsigned int* ph = (unsigned int*)(ws + PH_OFF);
  float* rowres = (float*)(ws + RR_OFF);
  unsigned int* lab4 = (unsigned int*)(ws + L4_OFF);

  norm_kernel<<<TOT / 4, 256, 0, stream>>>(inputs, bank, F4);
  pack_kernel<<<64, 256, 0, stream>>>(gt, bl, lab4, ph);
  gemm_kernel<<<(NQ / 128) * (TOT / 128), 256, 0, stream>>>(
      (const unsigned char*)F4, gt, lab4, ph);
  thresh_kernel<<<(NQ + 255) / 256, 256, 0, stream>>>(ph, rowres);
  final_kernel<<<1, 256, 0, stream>>>(rowres, out);
}

// Round 13
// 94.494 us; speedup vs baseline: 1.3132x; 1.3132x over previous
//
#include <hip/hip_runtime.h>
#include <hip/hip_bf16.h>

#define TOT 66560
#define NQ 1024
#define DIM 512
#define K_SEL 3328
#define SROW (TOT / 2)  // 33280 bytes per S4 row
#define NBK 16

typedef int i32x8 __attribute__((ext_vector_type(8)));
typedef float f32x4 __attribute__((ext_vector_type(4)));

__device__ __forceinline__ void gload_lds16(const void* g, void* l) {
  __builtin_amdgcn_global_load_lds(
      (const __attribute__((address_space(1))) unsigned int*)g,
      (__attribute__((address_space(3))) unsigned int*)l, 16, 0, 0);
}

// fp4 e2m1 encode, nearest: levels {0,0.5,1,1.5,2,3,4,6} = codes 0..7, sign<<3
__device__ __forceinline__ unsigned int fp4enc(float v) {
  float a = fabsf(v);
  unsigned int idx = (a > 0.25f) + (a > 0.75f) + (a > 1.25f) + (a > 1.75f) +
                     (a > 2.5f) + (a > 3.5f) + (a > 5.0f);
  return ((v < 0.f) ? 8u : 0u) | idx;
}

// ---------------- normalize rows -> fp4 matrix F4 (TOT x 512, 256 B/row) --
__global__ __launch_bounds__(256) void norm_kernel(
    const float* __restrict__ inputs, const float* __restrict__ bank,
    unsigned int* __restrict__ F4) {
  int row = blockIdx.x * 4 + (threadIdx.x >> 6);
  int lane = threadIdx.x & 63;
  const float* src = (row < NQ) ? (inputs + (size_t)row * DIM)
                                : (bank + (size_t)(row - NQ) * DIM);
  const float4 a = *(const float4*)(src + lane * 8);
  const float4 b = *(const float4*)(src + lane * 8 + 4);
  float ss = a.x * a.x + a.y * a.y + a.z * a.z + a.w * a.w +
             b.x * b.x + b.y * b.y + b.z * b.z + b.w * b.w;
#pragma unroll
  for (int off = 1; off < 64; off <<= 1) ss += __shfl_xor(ss, off);
  float sc = 32.0f / fmaxf(sqrtf(ss), 1e-12f);
  unsigned int w = fp4enc(a.x * sc) | (fp4enc(a.y * sc) << 4) |
                   (fp4enc(a.z * sc) << 8) | (fp4enc(a.w * sc) << 12) |
                   (fp4enc(b.x * sc) << 16) | (fp4enc(b.y * sc) << 20) |
                   (fp4enc(b.z * sc) << 24) | (fp4enc(b.w * sc) << 28);
  F4[(size_t)row * 64 + lane] = w;
}

// ---------------- pack labels to 4-bit nibbles (C=7 fits) -----------------
__global__ __launch_bounds__(256) void pack_kernel(
    const int* __restrict__ gt, const int* __restrict__ bl,
    unsigned int* __restrict__ lab4) {
  int i = blockIdx.x * 256 + threadIdx.x;  // packs labels [8i, 8i+8)
  if (i >= TOT / 8) return;
  unsigned int w = 0;
#pragma unroll
  for (int e = 0; e < 8; ++e) {
    int c = i * 8 + e;
    int l = (c < NQ) ? gt[c] : bl[c - NQ];
    w |= ((unsigned int)l & 0xFu) << (4 * e);
  }
  lab4[i] = w;
}

// ---------------- S4 = quantize_u4(F4[0:1024] * F4^T), MX-fp4 K=128 -------
// 128x128 tile, 4 waves, wave 64x64, acc[4][4]. Entire K=512 staged once,
// one barrier, 4x16 mfma_scale fp4. Epilogue: 16-bucket u4 keys, SWAR
// nibble-pack, 16B stores. Self-sim -> key 0.
__global__ __launch_bounds__(256, 2) void gemm_kernel(
    const unsigned char* __restrict__ F4, unsigned char* __restrict__ S4) {
  __shared__ unsigned char smem[65536];  // A[128][256B] | B[128][256B]

  // XCD-aware swizzle: 4160 blocks, 8 XCDs, 520 per XCD, bm fastest.
  int wgid = blockIdx.x;
  int xcd = wgid & 7;
  int local = wgid >> 3;
  int gid = xcd * 520 + local;
  int bm = gid & 7;   // row tile 0..7 (fastest: 8 blocks share a B panel)
  int bn = gid >> 3;  // col tile 0..519

  int tid = threadIdx.x;
  int lane = tid & 63, wave = tid >> 6;
  int wr = wave >> 1, wc = wave & 1;

  f32x4 acc[4][4];
#pragma unroll
  for (int m = 0; m < 4; ++m)
#pragma unroll
    for (int n = 0; n < 4; ++n) acc[m][n] = (f32x4){0.f, 0.f, 0.f, 0.f};

  int rowA0 = bm * 128;
  int rowB0 = bn * 128;

  // stage full K: rows are 256 B (16 chunks of 16 B); LDS dest linear,
  // global chunk = phys_chunk ^ (row & 15).
#pragma unroll
  for (int q = 0; q < 8; ++q) {
    int o = q * 4096 + tid * 16;
    int r = o >> 8;
    int cg = ((o >> 4) & 15) ^ (r & 15);
    gload_lds16(F4 + (size_t)(rowA0 + r) * 256 + cg * 16, smem + o);
  }
#pragma unroll
  for (int q = 0; q < 8; ++q) {
    int o = q * 4096 + tid * 16;
    int r = o >> 8;
    int cg = ((o >> 4) & 15) ^ (r & 15);
    gload_lds16(F4 + (size_t)(rowB0 + r) * 256 + cg * 16, smem + 32768 + o);
  }
  asm volatile("s_waitcnt vmcnt(0)" ::: "memory");
  __syncthreads();

  int g = lane >> 4;  // k-group 0..3 (32 k-elems = 16 B each)
  const unsigned char* At = smem;
  const unsigned char* Bt = smem + 32768;

#pragma unroll
  for (int t = 0; t < 4; ++t) {
    i32x8 af[4], bf[4];
#pragma unroll
    for (int m = 0; m < 4; ++m) {
      int r = wr * 64 + m * 16 + (lane & 15);
      int c = (4 * t + g) ^ (r & 15);
      uint4 v = *(const uint4*)(At + r * 256 + c * 16);
      af[m] = (i32x8){(int)v.x, (int)v.y, (int)v.z, (int)v.w, 0, 0, 0, 0};
    }
#pragma unroll
    for (int n = 0; n < 4; ++n) {
      int r = wc * 64 + n * 16 + (lane & 15);
      int c = (4 * t + g) ^ (r & 15);
      uint4 v = *(const uint4*)(Bt + r * 256 + c * 16);
      bf[n] = (i32x8){(int)v.x, (int)v.y, (int)v.z, (int)v.w, 0, 0, 0, 0};
    }
#pragma unroll
    for (int m = 0; m < 4; ++m)
#pragma unroll
      for (int n = 0; n < 4; ++n)
        acc[m][n] = __builtin_amdgcn_mfma_scale_f32_16x16x128_f8f6f4(
            af[m], bf[n], acc[m][n], 4 /*cbsz: fp4*/, 4 /*blgp: fp4*/,
            0, 0x7F7F7F7F /*scale A = 1.0*/, 0, 0x7F7F7F7F /*scale B = 1.0*/);
  }

  // epilogue: acc = 1024*sim; 16-bucket key (width 0.022 sim, center 8),
  // u8 keys into LDS, then SWAR nibble-pack + 16B stores (2 cols/byte).
  // C layout: col=lane&15, row=(lane>>4)*4+e. Self-sim (gr==gc) -> key 0.
  __syncthreads();
  unsigned char* osh = (unsigned char*)smem;  // [64][128] bytes
#pragma unroll
  for (int h = 0; h < 2; ++h) {
    if (wr == h) {
#pragma unroll
      for (int m = 0; m < 4; ++m)
#pragma unroll
        for (int n = 0; n < 4; ++n)
#pragma unroll
          for (int e = 0; e < 4; ++e) {
            int r = m * 16 + (lane >> 4) * 4 + e;     // 0..63
            int cc = wc * 64 + n * 16 + (lane & 15);  // 0..127
            int b = (int)fmaf(acc[m][n][e], 0.0443892f, 8.0f);
            b = min(max(b, 0), NBK - 1);
            int gr = bm * 128 + h * 64 + r;
            int gc = bn * 128 + cc;
            osh[r * 128 + cc] = (unsigned char)((gr == gc) ? 0 : b);
          }
    }
    __syncthreads();
    {
      int idx = tid * 32;  // 64 rows x 128 keys = 8192 B = 256 x 32
      uint4 lo = *(const uint4*)(osh + idx);
      uint4 hi = *(const uint4*)(osh + idx + 16);
      // keys <= 15 (high nibble of each byte 0): t = w | w>>4 packs pairs
      unsigned int t0 = lo.x | (lo.x >> 4), t1 = lo.y | (lo.y >> 4);
      unsigned int t2 = lo.z | (lo.z >> 4), t3 = lo.w | (lo.w >> 4);
      unsigned int u0 = hi.x | (hi.x >> 4), u1 = hi.y | (hi.y >> 4);
      unsigned int u2 = hi.z | (hi.z >> 4), u3 = hi.w | (hi.w >> 4);
      uint4 out;
      out.x = (t0 & 0xFFu) | ((t0 >> 8) & 0xFF00u) |
              ((t1 & 0xFFu) << 16) | ((t1 >> 8) & 0xFF00u) << 16;
      out.y = (t2 & 0xFFu) | ((t2 >> 8) & 0xFF00u) |
              ((t3 & 0xFFu) << 16) | ((t3 >> 8) & 0xFF00u) << 16;
      out.z = (u0 & 0xFFu) | ((u0 >> 8) & 0xFF00u) |
              ((u1 & 0xFFu) << 16) | ((u1 >> 8) & 0xFF00u) << 16;
      out.w = (u2 & 0xFFu) | ((u2 >> 8) & 0xFF00u) |
              ((u3 & 0xFFu) << 16) | ((u3 >> 8) & 0xFF00u) << 16;
      int r = tid >> 2;               // 0..63
      int cb = (tid & 3) * 16;        // byte offset within 64B row-half
      *(uint4*)(S4 + (size_t)(bm * 128 + h * 64 + r) * SROW + bn * 64 + cb) = out;
    }
    __syncthreads();
  }
}

// ---------------- fused per-row hist + threshold scan ---------------------
// per-THREAD private 16-bucket hist (stride 17 -> 2-way bank = free),
// ds_add fire-and-forget, SWAR label match, tree merge, in-block scan.
__global__ __launch_bounds__(256) void select_kernel(
    const unsigned char* __restrict__ S4, const int* __restrict__ gt,
    const unsigned int* __restrict__ lab4, float* __restrict__ rowres) {
  int row = blockIdx.x;
  int tid = threadIdx.x;
  __shared__ unsigned int h[256 * 17];
  __shared__ unsigned int part[256];
  __shared__ unsigned int fin[NBK];
  for (int i = tid; i < 256 * 17; i += 256) h[i] = 0;
  __syncthreads();
  unsigned int* hp = h + tid * 17;
  unsigned int myLbl4 = ((unsigned int)gt[row] & 0xFu) * 0x11111111u;
  const unsigned char* Sr = S4 + (size_t)row * SROW;
  const int NV = SROW / 16;  // 2080 16B chunks (32 cols each)
  for (int iv = tid; iv < NV; iv += 256) {
    uint4 kw = *(const uint4*)(Sr + iv * 16);        // 32 keys (nibbles)
    uint4 lw = *(const uint4*)(lab4 + iv * 4);       // 32 labels (nibbles)
    unsigned int kws[4] = {kw.x, kw.y, kw.z, kw.w};
    unsigned int lws[4] = {lw.x, lw.y, lw.z, lw.w};
#pragma unroll
    for (int wd = 0; wd < 4; ++wd) {
      unsigned int x = lws[wd] ^ myLbl4;  // nibbles 0..7 (labels < 8)
      unsigned int sm = ~(x | (x >> 1) | (x >> 2)) & 0x11111111u;  // ==myLbl
      unsigned int w = kws[wd];
#pragma unroll
      for (int e = 0; e < 8; ++e) {
        unsigned int k = (w >> (4 * e)) & 0xFu;
        unsigned int inc = 1u + (((sm >> (4 * e)) & 1u) << 16);
        atomicAdd(&hp[k], inc);  // private slot: no contention
      }
    }
  }
  __syncthreads();
  // tree merge: thread (g=tid>>4, b=tid&15) sums 16 copies
  {
    int g = tid >> 4, b = tid & 15;
    unsigned int s = 0;
#pragma unroll
    for (int c = 0; c < 16; ++c) s += h[(g * 16 + c) * 17 + b];
    part[tid] = s;
  }
  __syncthreads();
  if (tid < NBK) {
    unsigned int s = 0;
#pragma unroll
    for (int g = 0; g < 16; ++g) s += part[g * 16 + tid];
    fin[tid] = s;
  }
  __syncthreads();
  if (tid == 0) {
    unsigned int cum = 0, same = 0;
    float res = 0.f;
    for (int b = NBK - 1; b >= 0; --b) {
      unsigned int vv = fin[b];
      unsigned int cb = vv & 0xFFFFu, sb = vv >> 16;
      if (cum + cb >= (unsigned)K_SEL) {
        unsigned int need = (unsigned)K_SEL - cum;
        res = (float)same + (float)sb * ((float)need / (float)cb);
        break;
      }
      cum += cb;
      same += sb;
    }
    rowres[row] = res;
  }
}

// ---------------- final reduction ----------------------------------------
__global__ __launch_bounds__(256) void final_kernel(const float* __restrict__ rowres,
                                                    float* __restrict__ out) {
  int tid = threadIdx.x;
  float s = 0.f;
  for (int i = tid; i < NQ; i += 256) s += rowres[i];
  for (int off = 32; off; off >>= 1) s += __shfl_down(s, off);
  __shared__ float part[4];
  if ((tid & 63) == 0) part[tid >> 6] = s;
  __syncthreads();
  if (tid == 0) {
    float total = part[0] + part[1] + part[2] + part[3];
    out[0] = 1.0f - total / ((float)NQ * (float)K_SEL);
  }
}

extern "C" void kernel_launch(void* const* d_in, const int* in_sizes, int n_in,
                              void* d_out, int out_size, void* d_ws, size_t ws_size,
                              hipStream_t stream) {
  const float* inputs = (const float*)d_in[0];
  const int* gt = (const int*)d_in[1];
  const float* bank = (const float*)d_in[2];
  const int* bl = (const int*)d_in[3];
  float* out = (float*)d_out;

  char* ws = (char*)d_ws;
  const size_t F_OFF = 0;
  const size_t F_BYTES = (size_t)TOT * 256;  // 17,039,360 (fp4)
  const size_t S_OFF = F_OFF + F_BYTES;
  const size_t S_BYTES = (size_t)NQ * SROW;  // 34,078,720 (u4 keys)
  const size_t RR_OFF = S_OFF + S_BYTES;
  const size_t RR_BYTES = 4096;
  const size_t L4_OFF = RR_OFF + RR_BYTES;

  unsigned int* F4 = (unsigned int*)(ws + F_OFF);
  unsigned char* S4 = (unsigned char*)(ws + S_OFF);
  float* rowres = (float*)(ws + RR_OFF);
  unsigned int* lab4 = (unsigned int*)(ws + L4_OFF);

  norm_kernel<<<TOT / 4, 256, 0, stream>>>(inputs, bank, F4);
  pack_kernel<<<(TOT / 8 + 255) / 256, 256, 0, stream>>>(gt, bl, lab4);
  gemm_kernel<<<(NQ / 128) * (TOT / 128), 256, 0, stream>>>(
      (const unsigned char*)F4, S4);
  select_kernel<<<NQ, 256, 0, stream>>>(S4, gt, lab4, rowres);
  final_kernel<<<1, 256, 0, stream>>>(rowres, out);
}

// Round 14
// 92.689 us; speedup vs baseline: 1.3387x; 1.0195x over previous
//
#include <hip/hip_runtime.h>
#include <hip/hip_bf16.h>

#define TOT 66560
#define NQ 1024
#define DIM 512
#define K_SEL 3328
#define SROW (TOT / 2)  // 33280 bytes per S4 row
#define NBK 16

typedef int i32x8 __attribute__((ext_vector_type(8)));
typedef float f32x4 __attribute__((ext_vector_type(4)));

__device__ __forceinline__ void gload_lds16(const void* g, void* l) {
  __builtin_amdgcn_global_load_lds(
      (const __attribute__((address_space(1))) unsigned int*)g,
      (__attribute__((address_space(3))) unsigned int*)l, 16, 0, 0);
}

// fp4 e2m1 encode, nearest: levels {0,0.5,1,1.5,2,3,4,6} = codes 0..7, sign<<3
__device__ __forceinline__ unsigned int fp4enc(float v) {
  float a = fabsf(v);
  unsigned int idx = (a > 0.25f) + (a > 0.75f) + (a > 1.25f) + (a > 1.75f) +
                     (a > 2.5f) + (a > 3.5f) + (a > 5.0f);
  return ((v < 0.f) ? 8u : 0u) | idx;
}

// fence-protected barrier (rule #18)
#define FENCE_BAR()                    \
  do {                                 \
    __builtin_amdgcn_sched_barrier(0); \
    __builtin_amdgcn_s_barrier();      \
    __builtin_amdgcn_sched_barrier(0); \
  } while (0)

// ------- normalize rows -> fp4 matrix F4 (TOT x 512) + fused label pack ---
__global__ __launch_bounds__(256) void norm_kernel(
    const float* __restrict__ inputs, const float* __restrict__ bank,
    unsigned int* __restrict__ F4, const int* __restrict__ gt,
    const int* __restrict__ bl, unsigned int* __restrict__ lab4) {
  int row = blockIdx.x * 4 + (threadIdx.x >> 6);
  int lane = threadIdx.x & 63;
  const float* src = (row < NQ) ? (inputs + (size_t)row * DIM)
                                : (bank + (size_t)(row - NQ) * DIM);
  const float4 a = *(const float4*)(src + lane * 8);
  const float4 b = *(const float4*)(src + lane * 8 + 4);
  float ss = a.x * a.x + a.y * a.y + a.z * a.z + a.w * a.w +
             b.x * b.x + b.y * b.y + b.z * b.z + b.w * b.w;
#pragma unroll
  for (int off = 1; off < 64; off <<= 1) ss += __shfl_xor(ss, off);
  float sc = 32.0f / fmaxf(sqrtf(ss), 1e-12f);
  unsigned int w = fp4enc(a.x * sc) | (fp4enc(a.y * sc) << 4) |
                   (fp4enc(a.z * sc) << 8) | (fp4enc(a.w * sc) << 12) |
                   (fp4enc(b.x * sc) << 16) | (fp4enc(b.y * sc) << 20) |
                   (fp4enc(b.z * sc) << 24) | (fp4enc(b.w * sc) << 28);
  F4[(size_t)row * 64 + lane] = w;

  // fused label pack: first 33 blocks cover TOT/8 = 8320 words
  int gidx = blockIdx.x * 256 + threadIdx.x;
  if (gidx < TOT / 8) {
    unsigned int lw = 0;
#pragma unroll
    for (int e = 0; e < 8; ++e) {
      int c = gidx * 8 + e;
      int l = (c < NQ) ? gt[c] : bl[c - NQ];
      lw |= ((unsigned int)l & 0xFu) << (4 * e);
    }
    lab4[gidx] = lw;
  }
}

// ---------------- S4 = quantize_u4(F4[0:1024] * F4^T), MX-fp4 K=128 -------
// 128x128 tile, 4 waves, wave 64x64, acc[4][4]. K split into two planes
// ([half][row][128B], XOR (r&7) within plane): issue all 16 gload_lds,
// vmcnt(8) -> compute K-half 0 (32 MFMA) while half 1 lands, vmcnt(0) ->
// compute half 1. Epilogue: 16-bucket u4 keys, SWAR nibble-pack, 16B stores.
__global__ __launch_bounds__(256, 2) void gemm_kernel(
    const unsigned char* __restrict__ F4, unsigned char* __restrict__ S4) {
  __shared__ unsigned char smem[65536];  // A0|A1 (2x16KB), B0|B1 (2x16KB)

  // XCD-aware swizzle: 4160 blocks, 8 XCDs, 520 per XCD, bm fastest.
  int wgid = blockIdx.x;
  int xcd = wgid & 7;
  int local = wgid >> 3;
  int gid = xcd * 520 + local;
  int bm = gid & 7;   // row tile 0..7 (fastest: 8 blocks share a B panel)
  int bn = gid >> 3;  // col tile 0..519

  int tid = threadIdx.x;
  int lane = tid & 63, wave = tid >> 6;
  int wr = wave >> 1, wc = wave & 1;

  f32x4 acc[4][4];
#pragma unroll
  for (int m = 0; m < 4; ++m)
#pragma unroll
    for (int n = 0; n < 4; ++n) acc[m][n] = (f32x4){0.f, 0.f, 0.f, 0.f};

  int rowA0 = bm * 128;
  int rowB0 = bn * 128;

  // stage one K-half plane (16 KB = 4 gloads/thread): plane layout
  // [row][128B]; LDS dest linear per wave; global chunk = (ch ^ (r&7)) + 8h.
#define STAGE_PLANE(planeOff, row0, h)                              \
  do {                                                              \
    _Pragma("unroll") for (int q_ = 0; q_ < 4; ++q_) {              \
      int o_ = q_ * 4096 + tid * 16;                                \
      int r_ = o_ >> 7;                                             \
      int ch_ = (o_ >> 4) & 7;                                      \
      int cg_ = (ch_ ^ (r_ & 7)) + (h) * 8;                         \
      gload_lds16(F4 + (size_t)((row0) + r_) * 256 + cg_ * 16,      \
                  smem + (planeOff) + o_);                          \
    }                                                               \
  } while (0)

  STAGE_PLANE(0, rowA0, 0);      // A half 0
  STAGE_PLANE(32768, rowB0, 0);  // B half 0
  STAGE_PLANE(16384, rowA0, 1);  // A half 1
  STAGE_PLANE(49152, rowB0, 1);  // B half 1
#undef STAGE_PLANE
  asm volatile("s_waitcnt vmcnt(8)" ::: "memory");  // half 0 landed
  FENCE_BAR();

  int g = lane >> 4;  // k-subgroup 0..3 (16 B each)

#pragma unroll
  for (int p = 0; p < 2; ++p) {
    const unsigned char* Ap = smem + p * 16384;
    const unsigned char* Bp = smem + 32768 + p * 16384;
#pragma unroll
    for (int tt = 0; tt < 2; ++tt) {
      i32x8 af[4], bf[4];
#pragma unroll
      for (int m = 0; m < 4; ++m) {
        int r = wr * 64 + m * 16 + (lane & 15);
        int c = (tt * 4 + g) ^ (r & 7);
        uint4 v = *(const uint4*)(Ap + r * 128 + c * 16);
        af[m] = (i32x8){(int)v.x, (int)v.y, (int)v.z, (int)v.w, 0, 0, 0, 0};
      }
#pragma unroll
      for (int n = 0; n < 4; ++n) {
        int r = wc * 64 + n * 16 + (lane & 15);
        int c = (tt * 4 + g) ^ (r & 7);
        uint4 v = *(const uint4*)(Bp + r * 128 + c * 16);
        bf[n] = (i32x8){(int)v.x, (int)v.y, (int)v.z, (int)v.w, 0, 0, 0, 0};
      }
#pragma unroll
      for (int m = 0; m < 4; ++m)
#pragma unroll
        for (int n = 0; n < 4; ++n)
          acc[m][n] = __builtin_amdgcn_mfma_scale_f32_16x16x128_f8f6f4(
              af[m], bf[n], acc[m][n], 4 /*fp4*/, 4 /*fp4*/,
              0, 0x7F7F7F7F, 0, 0x7F7F7F7F);
    }
    if (p == 0) {
      asm volatile("s_waitcnt vmcnt(0)" ::: "memory");  // half 1 landed
      FENCE_BAR();                                      // visible to all waves
    }
  }

  // epilogue: acc = 1024*sim; 16-bucket key (width 0.022 sim, center 8),
  // u8 keys into LDS, then SWAR nibble-pack + 16B stores (2 cols/byte).
  // C layout: col=lane&15, row=(lane>>4)*4+e. Self-sim (gr==gc) -> key 0.
  __syncthreads();
  unsigned char* osh = (unsigned char*)smem;  // [64][128] bytes
#pragma unroll
  for (int h = 0; h < 2; ++h) {
    if (wr == h) {
#pragma unroll
      for (int m = 0; m < 4; ++m)
#pragma unroll
        for (int n = 0; n < 4; ++n)
#pragma unroll
          for (int e = 0; e < 4; ++e) {
            int r = m * 16 + (lane >> 4) * 4 + e;     // 0..63
            int cc = wc * 64 + n * 16 + (lane & 15);  // 0..127
            int b = (int)fmaf(acc[m][n][e], 0.0443892f, 8.0f);
            b = min(max(b, 0), NBK - 1);
            int gr = bm * 128 + h * 64 + r;
            int gc = bn * 128 + cc;
            osh[r * 128 + cc] = (unsigned char)((gr == gc) ? 0 : b);
          }
    }
    __syncthreads();
    {
      int idx = tid * 32;  // 64 rows x 128 keys = 8192 B = 256 x 32
      uint4 lo = *(const uint4*)(osh + idx);
      uint4 hi = *(const uint4*)(osh + idx + 16);
      unsigned int t0 = lo.x | (lo.x >> 4), t1 = lo.y | (lo.y >> 4);
      unsigned int t2 = lo.z | (lo.z >> 4), t3 = lo.w | (lo.w >> 4);
      unsigned int u0 = hi.x | (hi.x >> 4), u1 = hi.y | (hi.y >> 4);
      unsigned int u2 = hi.z | (hi.z >> 4), u3 = hi.w | (hi.w >> 4);
      uint4 out;
      out.x = (t0 & 0xFFu) | ((t0 >> 8) & 0xFF00u) |
              ((t1 & 0xFFu) << 16) | ((t1 >> 8) & 0xFF00u) << 16;
      out.y = (t2 & 0xFFu) | ((t2 >> 8) & 0xFF00u) |
              ((t3 & 0xFFu) << 16) | ((t3 >> 8) & 0xFF00u) << 16;
      out.z = (u0 & 0xFFu) | ((u0 >> 8) & 0xFF00u) |
              ((u1 & 0xFFu) << 16) | ((u1 >> 8) & 0xFF00u) << 16;
      out.w = (u2 & 0xFFu) | ((u2 >> 8) & 0xFF00u) |
              ((u3 & 0xFFu) << 16) | ((u3 >> 8) & 0xFF00u) << 16;
      int r = tid >> 2;
      int cb = (tid & 3) * 16;
      *(uint4*)(S4 + (size_t)(bm * 128 + h * 64 + r) * SROW + bn * 64 + cb) = out;
    }
    __syncthreads();
  }
}

// ---------------- fused per-row hist + threshold scan ---------------------
// per-THREAD private 16-bucket hist (stride 17 -> 2-way bank = free),
// SWAR label match, tree merge, in-block scan.
__global__ __launch_bounds__(256) void select_kernel(
    const unsigned char* __restrict__ S4, const int* __restrict__ gt,
    const unsigned int* __restrict__ lab4, float* __restrict__ rowres) {
  int row = blockIdx.x;
  int tid = threadIdx.x;
  __shared__ unsigned int h[256 * 17];
  __shared__ unsigned int part[256];
  __shared__ unsigned int fin[NBK];
  for (int i = tid; i < 256 * 17; i += 256) h[i] = 0;
  __syncthreads();
  unsigned int* hp = h + tid * 17;
  unsigned int myLbl4 = ((unsigned int)gt[row] & 0xFu) * 0x11111111u;
  const unsigned char* Sr = S4 + (size_t)row * SROW;
  const int NV = SROW / 16;  // 2080 16B chunks (32 cols each)
  for (int iv = tid; iv < NV; iv += 256) {
    uint4 kw = *(const uint4*)(Sr + iv * 16);   // 32 keys (nibbles)
    uint4 lw = *(const uint4*)(lab4 + iv * 4);  // 32 labels (nibbles)
    unsigned int kws[4] = {kw.x, kw.y, kw.z, kw.w};
    unsigned int lws[4] = {lw.x, lw.y, lw.z, lw.w};
#pragma unroll
    for (int wd = 0; wd < 4; ++wd) {
      unsigned int x = lws[wd] ^ myLbl4;  // nibbles 0..7 (labels < 8)
      unsigned int sm = ~(x | (x >> 1) | (x >> 2)) & 0x11111111u;  // ==myLbl
      unsigned int w = kws[wd];
#pragma unroll
      for (int e = 0; e < 8; ++e) {
        unsigned int k = (w >> (4 * e)) & 0xFu;
        unsigned int inc = 1u + (((sm >> (4 * e)) & 1u) << 16);
        atomicAdd(&hp[k], inc);  // private slot: no contention
      }
    }
  }
  __syncthreads();
  {
    int g = tid >> 4, b = tid & 15;
    unsigned int s = 0;
#pragma unroll
    for (int c = 0; c < 16; ++c) s += h[(g * 16 + c) * 17 + b];
    part[tid] = s;
  }
  __syncthreads();
  if (tid < NBK) {
    unsigned int s = 0;
#pragma unroll
    for (int g = 0; g < 16; ++g) s += part[g * 16 + tid];
    fin[tid] = s;
  }
  __syncthreads();
  if (tid == 0) {
    unsigned int cum = 0, same = 0;
    float res = 0.f;
    for (int b = NBK - 1; b >= 0; --b) {
      unsigned int vv = fin[b];
      unsigned int cb = vv & 0xFFFFu, sb = vv >> 16;
      if (cum + cb >= (unsigned)K_SEL) {
        unsigned int need = (unsigned)K_SEL - cum;
        res = (float)same + (float)sb * ((float)need / (float)cb);
        break;
      }
      cum += cb;
      same += sb;
    }
    rowres[row] = res;
  }
}

// ---------------- final reduction ----------------------------------------
__global__ __launch_bounds__(256) void final_kernel(const float* __restrict__ rowres,
                                                    float* __restrict__ out) {
  int tid = threadIdx.x;
  float s = 0.f;
  for (int i = tid; i < NQ; i += 256) s += rowres[i];
  for (int off = 32; off; off >>= 1) s += __shfl_down(s, off);
  __shared__ float part[4];
  if ((tid & 63) == 0) part[tid >> 6] = s;
  __syncthreads();
  if (tid == 0) {
    float total = part[0] + part[1] + part[2] + part[3];
    out[0] = 1.0f - total / ((float)NQ * (float)K_SEL);
  }
}

extern "C" void kernel_launch(void* const* d_in, const int* in_sizes, int n_in,
                              void* d_out, int out_size, void* d_ws, size_t ws_size,
                              hipStream_t stream) {
  const float* inputs = (const float*)d_in[0];
  const int* gt = (const int*)d_in[1];
  const float* bank = (const float*)d_in[2];
  const int* bl = (const int*)d_in[3];
  float* out = (float*)d_out;

  char* ws = (char*)d_ws;
  const size_t F_OFF = 0;
  const size_t F_BYTES = (size_t)TOT * 256;  // 17,039,360 (fp4)
  const size_t S_OFF = F_OFF + F_BYTES;
  const size_t S_BYTES = (size_t)NQ * SROW;  // 34,078,720 (u4 keys)
  const size_t RR_OFF = S_OFF + S_BYTES;
  const size_t RR_BYTES = 4096;
  const size_t L4_OFF = RR_OFF + RR_BYTES;

  unsigned int* F4 = (unsigned int*)(ws + F_OFF);
  unsigned char* S4 = (unsigned char*)(ws + S_OFF);
  float* rowres = (float*)(ws + RR_OFF);
  unsigned int* lab4 = (unsigned int*)(ws + L4_OFF);

  norm_kernel<<<TOT / 4, 256, 0, stream>>>(inputs, bank, F4, gt, bl, lab4);
  gemm_kernel<<<(NQ / 128) * (TOT / 128), 256, 0, stream>>>(
      (const unsigned char*)F4, S4);
  select_kernel<<<NQ, 256, 0, stream>>>(S4, gt, lab4, rowres);
  final_kernel<<<1, 256, 0, stream>>>(rowres, out);
}